// Round 2
// baseline (916.914 us; speedup 1.0000x reference)
//
#include <hip/hip_runtime.h>
#include <math.h>

#define NN   10000     // nodes
#define NBAT 4         // batch
#define NE   160000    // edges
#define FC   128       // concat feature dim (IN+OUT)
#define FO   64        // OUT
#define EPSV 1e-8f

// ---------------------------------------------------------------------------
// degree accumulation
__global__ void k_deg(const float* __restrict__ ew, const int* __restrict__ row,
                      const int* __restrict__ col, float* __restrict__ dout,
                      float* __restrict__ din) {
    int e = blockIdx.x * 256 + threadIdx.x;
    if (e < NE) {
        float w = ew[e];
        atomicAdd(&dout[row[e]], w);
        atomicAdd(&din[col[e]], w);
    }
}

__global__ void k_inv(float* __restrict__ dout, float* __restrict__ din) {
    int v = blockIdx.x * 256 + threadIdx.x;
    if (v < NN) {
        dout[v] = 1.f / (dout[v] + EPSV);
        din[v]  = 1.f / (din[v] + EPSV);
    }
}

// count incoming edges per destination for both CSRs
__global__ void k_count(const int* __restrict__ row, const int* __restrict__ col,
                        int* __restrict__ cnt_out, int* __restrict__ cnt_in) {
    int e = blockIdx.x * 256 + threadIdx.x;
    if (e < NE) {
        atomicAdd(&cnt_out[col[e]], 1);   // A_out scatters to col
        atomicAdd(&cnt_in[row[e]], 1);    // A_in  scatters to row
    }
}

// exclusive scan over N=10000 counts; blockIdx.x selects which CSR
__global__ void k_scan(const int* __restrict__ cnt_out, int* __restrict__ ptr_out, int* __restrict__ cur_out,
                       const int* __restrict__ cnt_in,  int* __restrict__ ptr_in,  int* __restrict__ cur_in) {
    const int* cnt = blockIdx.x ? cnt_in : cnt_out;
    int* ptr = blockIdx.x ? ptr_in : ptr_out;
    int* cur = blockIdx.x ? cur_in : cur_out;
    __shared__ int part[1024];
    int t = threadIdx.x;
    int c0 = t * 10, c1 = min(c0 + 10, NN);
    int s = 0;
    for (int i = c0; i < c1; i++) s += cnt[i];
    part[t] = s;
    __syncthreads();
    for (int off = 1; off < 1024; off <<= 1) {
        int v = (t >= off) ? part[t - off] : 0;
        __syncthreads();
        part[t] += v;
        __syncthreads();
    }
    int run = t ? part[t - 1] : 0;
    for (int i = c0; i < c1; i++) { ptr[i] = run; cur[i] = run; run += cnt[i]; }
    if (t == 1023) ptr[NN] = part[1023];
}

__global__ void k_fill(const int* __restrict__ row, const int* __restrict__ col,
                       const float* __restrict__ inv_out, const float* __restrict__ inv_in,
                       int* __restrict__ cur_out, int* __restrict__ srcs_out, float* __restrict__ w_out,
                       int* __restrict__ cur_in,  int* __restrict__ srcs_in,  float* __restrict__ w_in) {
    int e = blockIdx.x * 256 + threadIdx.x;
    if (e >= NE) return;
    int r = row[e], c = col[e];
    int po = atomicAdd(&cur_out[c], 1);
    srcs_out[po] = r;  w_out[po] = inv_out[r];   // weight depends on source's out-degree
    int pi = atomicAdd(&cur_in[r], 1);
    srcs_in[pi] = c;   w_in[pi] = inv_in[c];     // weight depends on source's in-degree
}

// ---------------------------------------------------------------------------
// propagation: y[b,v,:] = sum_j w[j] * x[b, src[j], :]   (gather form)
// special version reading the virtual concat [X|H]
__global__ void k_prop_xh(const int* __restrict__ ptr, const int* __restrict__ srcs,
                          const float* __restrict__ wts, const float* __restrict__ X,
                          const float* __restrict__ H, float* __restrict__ y) {
    int tid = blockIdx.x * 256 + threadIdx.x;      // NBAT*NN*128 threads
    int c = tid & 127;
    int v = (tid >> 7) % NN;
    int b = tid / (128 * NN);
    const float* src = (c < 64) ? (X + (size_t)b * NN * 64 + c)
                                : (H + (size_t)b * NN * 64 + (c - 64));
    int j0 = ptr[v], j1 = ptr[v + 1];
    float acc = 0.f;
    for (int j = j0; j < j1; j++) acc += wts[j] * src[(size_t)srcs[j] * 64];
    y[tid] = acc;
}

template <int D>
__global__ void k_prop(const int* __restrict__ ptr, const int* __restrict__ srcs,
                       const float* __restrict__ wts, const float* __restrict__ x,
                       float* __restrict__ y) {
    int tid = blockIdx.x * 256 + threadIdx.x;      // NBAT*NN*D threads
    int c = tid & (D - 1);
    int v = (tid / D) % NN;
    int b = tid / (D * NN);
    const float* src = x + (size_t)b * NN * D + c;
    int j0 = ptr[v], j1 = ptr[v + 1];
    float acc = 0.f;
    for (int j = j0; j < j1; j++) acc += wts[j] * src[(size_t)srcs[j] * D];
    y[tid] = acc;
}

// ---------------------------------------------------------------------------
// effective weights: Weff[g][kk][o], kk in [0,640)
//  blk0 (kk<128):   W00+W10-W02-W12
//  blk1: W01  blk2: W11  blk3: 2*W02  blk4: 2*W12
__global__ void k_wprep(const float* __restrict__ Wz, const float* __restrict__ Wr,
                        const float* __restrict__ Wh, float* __restrict__ Weff) {
    int t = blockIdx.x * 256 + threadIdx.x;
    if (t >= 3 * 640 * 64) return;
    int o = t & 63;
    int kk = (t >> 6) % 640;
    int g = t / (640 * 64);
    const float* W = (g == 0) ? Wz : (g == 1 ? Wr : Wh);
    int blk = kk >> 7, kin = kk & 127;
    // W index: ((d*3 + k)*128 + kin)*64 + o
#define WIDX(d, k) W[(((d) * 3 + (k)) * 128 + kin) * 64 + o]
    float val;
    if (blk == 0)      val = WIDX(0, 0) + WIDX(1, 0) - WIDX(0, 2) - WIDX(1, 2);
    else if (blk == 1) val = WIDX(0, 1);
    else if (blk == 2) val = WIDX(1, 1);
    else if (blk == 3) val = 2.f * WIDX(0, 2);
    else               val = 2.f * WIDX(1, 2);
#undef WIDX
    Weff[t] = val;
}

// ---------------------------------------------------------------------------
// tiled fp32 matmul: [40000, 640] @ [640, 64]; A assembled from 10 chunk sources
struct SrcTab {
    const float* p[10];
    int ld[10];
    int co[10];
};

__global__ __launch_bounds__(256) void k_gate_zr(SrcTab tab,
        const float* __restrict__ wz_eff, const float* __restrict__ wr_eff,
        const float* __restrict__ bz, const float* __restrict__ br,
        const float* __restrict__ H, float* __restrict__ Z, float* __restrict__ HR) {
    __shared__ float As[64][68];
    __shared__ float Wzs[64][64];
    __shared__ float Wrs[64][64];
    int tid = threadIdx.x;
    int tx = tid & 15, ty = tid >> 4;
    int rb0 = blockIdx.x * 64;
    float accZ[4][4] = {};
    float accR[4][4] = {};
    for (int ch = 0; ch < 10; ch++) {
        const float* sp = tab.p[ch];
        int ld = tab.ld[ch], co = tab.co[ch];
        {
            int k = tid & 63, m0 = tid >> 6;
            for (int m = m0; m < 64; m += 4)
                As[m][k] = sp[(size_t)(rb0 + m) * ld + co + k];
        }
        {
            int o = tid & 63, k0 = tid >> 6;
            for (int k = k0; k < 64; k += 4) {
                Wzs[k][o] = wz_eff[(ch * 64 + k) * 64 + o];
                Wrs[k][o] = wr_eff[(ch * 64 + k) * 64 + o];
            }
        }
        __syncthreads();
        for (int kk = 0; kk < 64; kk++) {
            float a[4];
#pragma unroll
            for (int i = 0; i < 4; i++) a[i] = As[ty * 4 + i][kk];
            float4 wz4 = *(const float4*)&Wzs[kk][tx * 4];
            float4 wr4 = *(const float4*)&Wrs[kk][tx * 4];
            float wz[4] = {wz4.x, wz4.y, wz4.z, wz4.w};
            float wr[4] = {wr4.x, wr4.y, wr4.z, wr4.w};
#pragma unroll
            for (int i = 0; i < 4; i++)
#pragma unroll
                for (int j = 0; j < 4; j++) {
                    accZ[i][j] += a[i] * wz[j];
                    accR[i][j] += a[i] * wr[j];
                }
        }
        __syncthreads();
    }
#pragma unroll
    for (int i = 0; i < 4; i++) {
        int rb = rb0 + ty * 4 + i;
#pragma unroll
        for (int j = 0; j < 4; j++) {
            int o = tx * 4 + j;
            float z = 1.f / (1.f + __expf(-(accZ[i][j] + bz[o])));
            float r = 1.f / (1.f + __expf(-(accR[i][j] + br[o])));
            Z[(size_t)rb * 64 + o] = z;
            HR[(size_t)rb * 64 + o] = H[(size_t)rb * 64 + o] * r;
        }
    }
}

__global__ __launch_bounds__(256) void k_gate_h(SrcTab tab,
        const float* __restrict__ wh_eff, const float* __restrict__ bh,
        const float* __restrict__ H, const float* __restrict__ Z,
        float* __restrict__ out) {
    __shared__ float As[64][68];
    __shared__ float Ws[64][64];
    int tid = threadIdx.x;
    int tx = tid & 15, ty = tid >> 4;
    int rb0 = blockIdx.x * 64;
    float acc[4][4] = {};
    for (int ch = 0; ch < 10; ch++) {
        const float* sp = tab.p[ch];
        int ld = tab.ld[ch], co = tab.co[ch];
        {
            int k = tid & 63, m0 = tid >> 6;
            for (int m = m0; m < 64; m += 4)
                As[m][k] = sp[(size_t)(rb0 + m) * ld + co + k];
        }
        {
            int o = tid & 63, k0 = tid >> 6;
            for (int k = k0; k < 64; k += 4)
                Ws[k][o] = wh_eff[(ch * 64 + k) * 64 + o];
        }
        __syncthreads();
        for (int kk = 0; kk < 64; kk++) {
            float a[4];
#pragma unroll
            for (int i = 0; i < 4; i++) a[i] = As[ty * 4 + i][kk];
            float4 w4 = *(const float4*)&Ws[kk][tx * 4];
            float w[4] = {w4.x, w4.y, w4.z, w4.w};
#pragma unroll
            for (int i = 0; i < 4; i++)
#pragma unroll
                for (int j = 0; j < 4; j++) acc[i][j] += a[i] * w[j];
        }
        __syncthreads();
    }
#pragma unroll
    for (int i = 0; i < 4; i++) {
        int rb = rb0 + ty * 4 + i;
#pragma unroll
        for (int j = 0; j < 4; j++) {
            int o = tx * 4 + j;
            float ht = tanhf(acc[i][j] + bh[o]);
            float z = Z[(size_t)rb * 64 + o];
            out[(size_t)rb * 64 + o] = z * H[(size_t)rb * 64 + o] + (1.f - z) * ht;
        }
    }
}

// ---------------------------------------------------------------------------
extern "C" void kernel_launch(void* const* d_in, const int* in_sizes, int n_in,
                              void* d_out, int out_size, void* d_ws, size_t ws_size,
                              hipStream_t stream) {
    const float* X  = (const float*)d_in[0];
    const float* H  = (const float*)d_in[1];
    const float* ew = (const float*)d_in[2];
    const float* Wz = (const float*)d_in[3];
    const float* bz = (const float*)d_in[4];
    const float* Wr = (const float*)d_in[5];
    const float* br = (const float*)d_in[6];
    const float* Wh = (const float*)d_in[7];
    const float* bh = (const float*)d_in[8];
    const int*   ei = (const int*)d_in[9];
    const int* row = ei;
    const int* col = ei + NE;
    float* out = (float*)d_out;

    char* ws = (char*)d_ws;
    size_t off = 0;
    auto alloc = [&](size_t bytes) -> void* {
        void* p = ws + off;
        off += (bytes + 255) & ~(size_t)255;
        return p;
    };
    float* degs     = (float*)alloc(2 * NN * 4);           // deg_out | deg_in (then inverted)
    int*   cnts     = (int*)alloc(2 * NN * 4);             // cnt_out | cnt_in
    int*   ptr_out  = (int*)alloc((NN + 1) * 4);
    int*   cur_out  = (int*)alloc(NN * 4);
    int*   srcs_out = (int*)alloc(NE * 4);
    float* w_out    = (float*)alloc(NE * 4);
    int*   ptr_in   = (int*)alloc((NN + 1) * 4);
    int*   cur_in   = (int*)alloc(NN * 4);
    int*   srcs_in  = (int*)alloc(NE * 4);
    float* w_in     = (float*)alloc(NE * 4);
    const size_t nBN = (size_t)NBAT * NN;
    float* P1o = (float*)alloc(nBN * 128 * 4);
    float* P1i = (float*)alloc(nBN * 128 * 4);
    float* S1o = (float*)alloc(nBN * 128 * 4);
    float* S1i = (float*)alloc(nBN * 128 * 4);
    float* Zb  = (float*)alloc(nBN * 64 * 4);
    float* HRb = (float*)alloc(nBN * 64 * 4);
    float* T1o = (float*)alloc(nBN * 64 * 4);
    float* T1i = (float*)alloc(nBN * 64 * 4);
    float* T2o = (float*)alloc(nBN * 64 * 4);
    float* T2i = (float*)alloc(nBN * 64 * 4);
    float* weff = (float*)alloc(3 * 640 * 64 * 4);
    float* wz_eff = weff;
    float* wr_eff = weff + 640 * 64;
    float* wh_eff = weff + 2 * 640 * 64;

    float* deg_out = degs;
    float* deg_in  = degs + NN;
    int* cnt_out = cnts;
    int* cnt_in  = cnts + NN;

    hipMemsetAsync(degs, 0, 2 * NN * 4, stream);
    hipMemsetAsync(cnts, 0, 2 * NN * 4, stream);

    int gE = (NE + 255) / 256;
    k_deg<<<gE, 256, 0, stream>>>(ew, row, col, deg_out, deg_in);
    k_inv<<<(NN + 255) / 256, 256, 0, stream>>>(deg_out, deg_in);
    k_count<<<gE, 256, 0, stream>>>(row, col, cnt_out, cnt_in);
    k_scan<<<2, 1024, 0, stream>>>(cnt_out, ptr_out, cur_out, cnt_in, ptr_in, cur_in);
    k_fill<<<gE, 256, 0, stream>>>(row, col, deg_out, deg_in,
                                   cur_out, srcs_out, w_out, cur_in, srcs_in, w_in);

    int g128 = (int)(nBN * 128 / 256);
    int g64  = (int)(nBN * 64 / 256);
    // P1o = A_out [X|H], P1i = A_in [X|H]
    k_prop_xh<<<g128, 256, 0, stream>>>(ptr_out, srcs_out, w_out, X, H, P1o);
    k_prop_xh<<<g128, 256, 0, stream>>>(ptr_in, srcs_in, w_in, X, H, P1i);
    // S1o = A_out P1o, S1i = A_in P1i
    k_prop<128><<<g128, 256, 0, stream>>>(ptr_out, srcs_out, w_out, P1o, S1o);
    k_prop<128><<<g128, 256, 0, stream>>>(ptr_in, srcs_in, w_in, P1i, S1i);

    k_wprep<<<(3 * 640 * 64 + 255) / 256, 256, 0, stream>>>(Wz, Wr, Wh, weff);

    SrcTab zr;
    {
        const float* ps[10] = {X, H, P1o, P1o, P1i, P1i, S1o, S1o, S1i, S1i};
        int lds[10] = {64, 64, 128, 128, 128, 128, 128, 128, 128, 128};
        int cos_[10] = {0, 0, 0, 64, 0, 64, 0, 64, 0, 64};
        for (int i = 0; i < 10; i++) { zr.p[i] = ps[i]; zr.ld[i] = lds[i]; zr.co[i] = cos_[i]; }
    }
    int gMM = (int)(nBN / 64);
    k_gate_zr<<<gMM, 256, 0, stream>>>(zr, wz_eff, wr_eff, bz, br, H, Zb, HRb);

    // props of HR (64-dim)
    k_prop<64><<<g64, 256, 0, stream>>>(ptr_out, srcs_out, w_out, HRb, T1o);
    k_prop<64><<<g64, 256, 0, stream>>>(ptr_in, srcs_in, w_in, HRb, T1i);
    k_prop<64><<<g64, 256, 0, stream>>>(ptr_out, srcs_out, w_out, T1o, T2o);
    k_prop<64><<<g64, 256, 0, stream>>>(ptr_in, srcs_in, w_in, T1i, T2i);

    SrcTab hh;
    {
        const float* ps[10] = {X, HRb, P1o, T1o, P1i, T1i, S1o, T2o, S1i, T2i};
        int lds[10] = {64, 64, 128, 64, 128, 64, 128, 64, 128, 64};
        int cos_[10] = {0, 0, 0, 0, 0, 0, 0, 0, 0, 0};
        for (int i = 0; i < 10; i++) { hh.p[i] = ps[i]; hh.ld[i] = lds[i]; hh.co[i] = cos_[i]; }
    }
    k_gate_h<<<gMM, 256, 0, stream>>>(hh, wh_eff, bh, H, Zb, out);
}

// Round 3
// 441.252 us; speedup vs baseline: 2.0780x; 2.0780x over previous
//
#include <hip/hip_runtime.h>
#include <math.h>

#define NN   10000     // nodes
#define NBAT 4         // batch
#define NE   160000    // edges
#define EPSV 1e-8f

// ---------------------------------------------------------------------------
// degree accumulation
__global__ void k_deg(const float* __restrict__ ew, const int* __restrict__ row,
                      const int* __restrict__ col, float* __restrict__ dout,
                      float* __restrict__ din) {
    int e = blockIdx.x * 256 + threadIdx.x;
    if (e < NE) {
        float w = ew[e];
        atomicAdd(&dout[row[e]], w);
        atomicAdd(&din[col[e]], w);
    }
}

__global__ void k_inv(float* __restrict__ dout, float* __restrict__ din) {
    int v = blockIdx.x * 256 + threadIdx.x;
    if (v < NN) {
        dout[v] = 1.f / (dout[v] + EPSV);
        din[v]  = 1.f / (din[v] + EPSV);
    }
}

// count incoming edges per destination for both CSRs
__global__ void k_count(const int* __restrict__ row, const int* __restrict__ col,
                        int* __restrict__ cnt_out, int* __restrict__ cnt_in) {
    int e = blockIdx.x * 256 + threadIdx.x;
    if (e < NE) {
        atomicAdd(&cnt_out[col[e]], 1);   // A_out scatters to col
        atomicAdd(&cnt_in[row[e]], 1);    // A_in  scatters to row
    }
}

// exclusive scan over N=10000 counts; blockIdx.x selects which CSR
__global__ void k_scan(const int* __restrict__ cnt_out, int* __restrict__ ptr_out, int* __restrict__ cur_out,
                       const int* __restrict__ cnt_in,  int* __restrict__ ptr_in,  int* __restrict__ cur_in) {
    const int* cnt = blockIdx.x ? cnt_in : cnt_out;
    int* ptr = blockIdx.x ? ptr_in : ptr_out;
    int* cur = blockIdx.x ? cur_in : cur_out;
    __shared__ int part[1024];
    int t = threadIdx.x;
    int c0 = t * 10, c1 = min(c0 + 10, NN);
    int s = 0;
    for (int i = c0; i < c1; i++) s += cnt[i];
    part[t] = s;
    __syncthreads();
    for (int off = 1; off < 1024; off <<= 1) {
        int v = (t >= off) ? part[t - off] : 0;
        __syncthreads();
        part[t] += v;
        __syncthreads();
    }
    int run = t ? part[t - 1] : 0;
    for (int i = c0; i < c1; i++) { ptr[i] = run; cur[i] = run; run += cnt[i]; }
    if (t == 1023) ptr[NN] = part[1023];
}

__global__ void k_fill(const int* __restrict__ row, const int* __restrict__ col,
                       const float* __restrict__ inv_out, const float* __restrict__ inv_in,
                       int* __restrict__ cur_out, int* __restrict__ srcs_out, float* __restrict__ w_out,
                       int* __restrict__ cur_in,  int* __restrict__ srcs_in,  float* __restrict__ w_in) {
    int e = blockIdx.x * 256 + threadIdx.x;
    if (e >= NE) return;
    int r = row[e], c = col[e];
    int po = atomicAdd(&cur_out[c], 1);
    srcs_out[po] = r;  w_out[po] = inv_out[r];   // weight depends on source's out-degree
    int pi = atomicAdd(&cur_in[r], 1);
    srcs_in[pi] = c;   w_in[pi] = inv_in[c];     // weight depends on source's in-degree
}

// ---------------------------------------------------------------------------
// propagation, float4-vectorized, two CSRs merged into one launch.
// y[b,v,:] = sum_j w[j] * x[b, src[j], :]
// Virtual-concat version: input rows are [X[b,v,:64] | H[b,v,:64]] (D=128).
__global__ __launch_bounds__(256) void k_prop_xh2(
        const int* __restrict__ pA, const int* __restrict__ sA, const float* __restrict__ wA,
        float* __restrict__ yA,
        const int* __restrict__ pB, const int* __restrict__ sB, const float* __restrict__ wB,
        float* __restrict__ yB,
        const float* __restrict__ X, const float* __restrict__ H) {
    int half = gridDim.x >> 1;
    bool second = blockIdx.x >= half;
    const int* ptr    = second ? pB : pA;
    const int* srcs   = second ? sB : sA;
    const float* wts  = second ? wB : wA;
    float* y          = second ? yB : yA;
    int tid = (second ? blockIdx.x - half : blockIdx.x) * 256 + threadIdx.x;
    // D=128 -> 32 float4 lanes per node
    int c4 = tid & 31;
    int v  = (tid >> 5) % NN;
    int b  = tid / (32 * NN);
    const float4* src = (c4 < 16)
        ? ((const float4*)(X + (size_t)b * NN * 64) + c4)
        : ((const float4*)(H + (size_t)b * NN * 64) + (c4 - 16));
    int j0 = ptr[v], j1 = ptr[v + 1];
    float4 acc = {0.f, 0.f, 0.f, 0.f};
#pragma unroll 4
    for (int j = j0; j < j1; j++) {
        float w = wts[j];
        float4 g = src[(size_t)srcs[j] * 16];
        acc.x += w * g.x; acc.y += w * g.y; acc.z += w * g.z; acc.w += w * g.w;
    }
    ((float4*)y)[tid] = acc;
}

template <int D>
__global__ __launch_bounds__(256) void k_prop2(
        const int* __restrict__ pA, const int* __restrict__ sA, const float* __restrict__ wA,
        const float* __restrict__ xA, float* __restrict__ yA,
        const int* __restrict__ pB, const int* __restrict__ sB, const float* __restrict__ wB,
        const float* __restrict__ xB, float* __restrict__ yB) {
    const int VEC = D / 4;   // float4 lanes per node
    int half = gridDim.x >> 1;
    bool second = blockIdx.x >= half;
    const int* ptr    = second ? pB : pA;
    const int* srcs   = second ? sB : sA;
    const float* wts  = second ? wB : wA;
    const float* x    = second ? xB : xA;
    float* y          = second ? yB : yA;
    int tid = (second ? blockIdx.x - half : blockIdx.x) * 256 + threadIdx.x;
    int c4 = tid & (VEC - 1);
    int v  = (tid / VEC) % NN;
    int b  = tid / (VEC * NN);
    const float4* src = (const float4*)(x + (size_t)b * NN * D) + c4;
    int j0 = ptr[v], j1 = ptr[v + 1];
    float4 acc = {0.f, 0.f, 0.f, 0.f};
#pragma unroll 4
    for (int j = j0; j < j1; j++) {
        float w = wts[j];
        float4 g = src[(size_t)srcs[j] * VEC];
        acc.x += w * g.x; acc.y += w * g.y; acc.z += w * g.z; acc.w += w * g.w;
    }
    ((float4*)y)[tid] = acc;
}

// ---------------------------------------------------------------------------
// effective weights: Weff[g][kk][o], kk in [0,640)
//  blk0 (kk<128):   W00+W10-W02-W12
//  blk1: W01  blk2: W11  blk3: 2*W02  blk4: 2*W12
__global__ void k_wprep(const float* __restrict__ Wz, const float* __restrict__ Wr,
                        const float* __restrict__ Wh, float* __restrict__ Weff) {
    int t = blockIdx.x * 256 + threadIdx.x;
    if (t >= 3 * 640 * 64) return;
    int o = t & 63;
    int kk = (t >> 6) % 640;
    int g = t / (640 * 64);
    const float* W = (g == 0) ? Wz : (g == 1 ? Wr : Wh);
    int blk = kk >> 7, kin = kk & 127;
    // W index: ((d*3 + k)*128 + kin)*64 + o
#define WIDX(d, k) W[(((d) * 3 + (k)) * 128 + kin) * 64 + o]
    float val;
    if (blk == 0)      val = WIDX(0, 0) + WIDX(1, 0) - WIDX(0, 2) - WIDX(1, 2);
    else if (blk == 1) val = WIDX(0, 1);
    else if (blk == 2) val = WIDX(1, 1);
    else if (blk == 3) val = 2.f * WIDX(0, 2);
    else               val = 2.f * WIDX(1, 2);
#undef WIDX
    Weff[t] = val;
}

// ---------------------------------------------------------------------------
// tiled fp32 matmul: [40000, 640] @ [640, 64]; A assembled from 10 chunk sources
struct SrcTab {
    const float* p[10];
    int ld[10];
    int co[10];
};

__global__ __launch_bounds__(256) void k_gate_zr(SrcTab tab,
        const float* __restrict__ wz_eff, const float* __restrict__ wr_eff,
        const float* __restrict__ bz, const float* __restrict__ br,
        const float* __restrict__ H, float* __restrict__ Z, float* __restrict__ HR) {
    __shared__ float As[64][68];
    __shared__ float Wzs[64][64];
    __shared__ float Wrs[64][64];
    int tid = threadIdx.x;
    int tx = tid & 15, ty = tid >> 4;
    int rb0 = blockIdx.x * 64;
    float accZ[4][4] = {};
    float accR[4][4] = {};
    for (int ch = 0; ch < 10; ch++) {
        const float* sp = tab.p[ch];
        int ld = tab.ld[ch], co = tab.co[ch];
        {
            int k = tid & 63, m0 = tid >> 6;
            for (int m = m0; m < 64; m += 4)
                As[m][k] = sp[(size_t)(rb0 + m) * ld + co + k];
        }
        {
            int o = tid & 63, k0 = tid >> 6;
            for (int k = k0; k < 64; k += 4) {
                Wzs[k][o] = wz_eff[(ch * 64 + k) * 64 + o];
                Wrs[k][o] = wr_eff[(ch * 64 + k) * 64 + o];
            }
        }
        __syncthreads();
        for (int kk = 0; kk < 64; kk++) {
            float a[4];
#pragma unroll
            for (int i = 0; i < 4; i++) a[i] = As[ty * 4 + i][kk];
            float4 wz4 = *(const float4*)&Wzs[kk][tx * 4];
            float4 wr4 = *(const float4*)&Wrs[kk][tx * 4];
            float wz[4] = {wz4.x, wz4.y, wz4.z, wz4.w};
            float wr[4] = {wr4.x, wr4.y, wr4.z, wr4.w};
#pragma unroll
            for (int i = 0; i < 4; i++)
#pragma unroll
                for (int j = 0; j < 4; j++) {
                    accZ[i][j] += a[i] * wz[j];
                    accR[i][j] += a[i] * wr[j];
                }
        }
        __syncthreads();
    }
#pragma unroll
    for (int i = 0; i < 4; i++) {
        int rb = rb0 + ty * 4 + i;
#pragma unroll
        for (int j = 0; j < 4; j++) {
            int o = tx * 4 + j;
            float z = 1.f / (1.f + __expf(-(accZ[i][j] + bz[o])));
            float r = 1.f / (1.f + __expf(-(accR[i][j] + br[o])));
            Z[(size_t)rb * 64 + o] = z;
            HR[(size_t)rb * 64 + o] = H[(size_t)rb * 64 + o] * r;
        }
    }
}

__global__ __launch_bounds__(256) void k_gate_h(SrcTab tab,
        const float* __restrict__ wh_eff, const float* __restrict__ bh,
        const float* __restrict__ H, const float* __restrict__ Z,
        float* __restrict__ out) {
    __shared__ float As[64][68];
    __shared__ float Ws[64][64];
    int tid = threadIdx.x;
    int tx = tid & 15, ty = tid >> 4;
    int rb0 = blockIdx.x * 64;
    float acc[4][4] = {};
    for (int ch = 0; ch < 10; ch++) {
        const float* sp = tab.p[ch];
        int ld = tab.ld[ch], co = tab.co[ch];
        {
            int k = tid & 63, m0 = tid >> 6;
            for (int m = m0; m < 64; m += 4)
                As[m][k] = sp[(size_t)(rb0 + m) * ld + co + k];
        }
        {
            int o = tid & 63, k0 = tid >> 6;
            for (int k = k0; k < 64; k += 4)
                Ws[k][o] = wh_eff[(ch * 64 + k) * 64 + o];
        }
        __syncthreads();
        for (int kk = 0; kk < 64; kk++) {
            float a[4];
#pragma unroll
            for (int i = 0; i < 4; i++) a[i] = As[ty * 4 + i][kk];
            float4 w4 = *(const float4*)&Ws[kk][tx * 4];
            float w[4] = {w4.x, w4.y, w4.z, w4.w};
#pragma unroll
            for (int i = 0; i < 4; i++)
#pragma unroll
                for (int j = 0; j < 4; j++) acc[i][j] += a[i] * w[j];
        }
        __syncthreads();
    }
#pragma unroll
    for (int i = 0; i < 4; i++) {
        int rb = rb0 + ty * 4 + i;
#pragma unroll
        for (int j = 0; j < 4; j++) {
            int o = tx * 4 + j;
            float ht = tanhf(acc[i][j] + bh[o]);
            float z = Z[(size_t)rb * 64 + o];
            out[(size_t)rb * 64 + o] = z * H[(size_t)rb * 64 + o] + (1.f - z) * ht;
        }
    }
}

// ---------------------------------------------------------------------------
extern "C" void kernel_launch(void* const* d_in, const int* in_sizes, int n_in,
                              void* d_out, int out_size, void* d_ws, size_t ws_size,
                              hipStream_t stream) {
    const float* X  = (const float*)d_in[0];
    const float* H  = (const float*)d_in[1];
    const float* ew = (const float*)d_in[2];
    const float* Wz = (const float*)d_in[3];
    const float* bz = (const float*)d_in[4];
    const float* Wr = (const float*)d_in[5];
    const float* br = (const float*)d_in[6];
    const float* Wh = (const float*)d_in[7];
    const float* bh = (const float*)d_in[8];
    const int*   ei = (const int*)d_in[9];
    const int* row = ei;
    const int* col = ei + NE;
    float* out = (float*)d_out;

    char* ws = (char*)d_ws;
    size_t off = 0;
    auto alloc = [&](size_t bytes) -> void* {
        void* p = ws + off;
        off += (bytes + 255) & ~(size_t)255;
        return p;
    };
    float* degs     = (float*)alloc(2 * NN * 4);           // deg_out | deg_in (then inverted)
    int*   cnts     = (int*)alloc(2 * NN * 4);             // cnt_out | cnt_in
    int*   ptr_out  = (int*)alloc((NN + 1) * 4);
    int*   cur_out  = (int*)alloc(NN * 4);
    int*   srcs_out = (int*)alloc(NE * 4);
    float* w_out    = (float*)alloc(NE * 4);
    int*   ptr_in   = (int*)alloc((NN + 1) * 4);
    int*   cur_in   = (int*)alloc(NN * 4);
    int*   srcs_in  = (int*)alloc(NE * 4);
    float* w_in     = (float*)alloc(NE * 4);
    const size_t nBN = (size_t)NBAT * NN;
    float* P1o = (float*)alloc(nBN * 128 * 4);
    float* P1i = (float*)alloc(nBN * 128 * 4);
    float* S1o = (float*)alloc(nBN * 128 * 4);
    float* S1i = (float*)alloc(nBN * 128 * 4);
    float* Zb  = (float*)alloc(nBN * 64 * 4);
    float* HRb = (float*)alloc(nBN * 64 * 4);
    float* T1o = (float*)alloc(nBN * 64 * 4);
    float* T1i = (float*)alloc(nBN * 64 * 4);
    float* T2o = (float*)alloc(nBN * 64 * 4);
    float* T2i = (float*)alloc(nBN * 64 * 4);
    float* weff = (float*)alloc(3 * 640 * 64 * 4);
    float* wz_eff = weff;
    float* wr_eff = weff + 640 * 64;
    float* wh_eff = weff + 2 * 640 * 64;

    float* deg_out = degs;
    float* deg_in  = degs + NN;
    int* cnt_out = cnts;
    int* cnt_in  = cnts + NN;

    hipMemsetAsync(degs, 0, 2 * NN * 4, stream);
    hipMemsetAsync(cnts, 0, 2 * NN * 4, stream);

    int gE = (NE + 255) / 256;
    k_deg<<<gE, 256, 0, stream>>>(ew, row, col, deg_out, deg_in);
    k_inv<<<(NN + 255) / 256, 256, 0, stream>>>(deg_out, deg_in);
    k_count<<<gE, 256, 0, stream>>>(row, col, cnt_out, cnt_in);
    k_scan<<<2, 1024, 0, stream>>>(cnt_out, ptr_out, cur_out, cnt_in, ptr_in, cur_in);
    k_fill<<<gE, 256, 0, stream>>>(row, col, deg_out, deg_in,
                                   cur_out, srcs_out, w_out, cur_in, srcs_in, w_in);

    // merged prop launches: half the grid = out-CSR, half = in-CSR
    int g128x2 = (int)(2 * nBN * 32 / 256);   // D=128, float4 lanes
    int g64x2  = (int)(2 * nBN * 16 / 256);   // D=64

    // P1o = A_out [X|H], P1i = A_in [X|H]
    k_prop_xh2<<<g128x2, 256, 0, stream>>>(ptr_out, srcs_out, w_out, P1o,
                                           ptr_in, srcs_in, w_in, P1i, X, H);
    // S1o = A_out P1o, S1i = A_in P1i
    k_prop2<128><<<g128x2, 256, 0, stream>>>(ptr_out, srcs_out, w_out, P1o, S1o,
                                             ptr_in, srcs_in, w_in, P1i, S1i);

    k_wprep<<<(3 * 640 * 64 + 255) / 256, 256, 0, stream>>>(Wz, Wr, Wh, weff);

    SrcTab zr;
    {
        const float* ps[10] = {X, H, P1o, P1o, P1i, P1i, S1o, S1o, S1i, S1i};
        int lds[10] = {64, 64, 128, 128, 128, 128, 128, 128, 128, 128};
        int cos_[10] = {0, 0, 0, 64, 0, 64, 0, 64, 0, 64};
        for (int i = 0; i < 10; i++) { zr.p[i] = ps[i]; zr.ld[i] = lds[i]; zr.co[i] = cos_[i]; }
    }
    int gMM = (int)(nBN / 64);
    k_gate_zr<<<gMM, 256, 0, stream>>>(zr, wz_eff, wr_eff, bz, br, H, Zb, HRb);

    // props of HR (64-dim): T1o = A_out HR, T1i = A_in HR
    k_prop2<64><<<g64x2, 256, 0, stream>>>(ptr_out, srcs_out, w_out, HRb, T1o,
                                           ptr_in, srcs_in, w_in, HRb, T1i);
    // T2o = A_out T1o, T2i = A_in T1i
    k_prop2<64><<<g64x2, 256, 0, stream>>>(ptr_out, srcs_out, w_out, T1o, T2o,
                                           ptr_in, srcs_in, w_in, T1i, T2i);

    SrcTab hh;
    {
        const float* ps[10] = {X, HRb, P1o, T1o, P1i, T1i, S1o, T2o, S1i, T2i};
        int lds[10] = {64, 64, 128, 64, 128, 64, 128, 64, 128, 64};
        int cos_[10] = {0, 0, 0, 0, 0, 0, 0, 0, 0, 0};
        for (int i = 0; i < 10; i++) { hh.p[i] = ps[i]; hh.ld[i] = lds[i]; hh.co[i] = cos_[i]; }
    }
    k_gate_h<<<gMM, 256, 0, stream>>>(hh, wh_eff, bh, H, Zb, out);
}

// Round 4
// 250.479 us; speedup vs baseline: 3.6606x; 1.7616x over previous
//
#include <hip/hip_runtime.h>
#include <math.h>

#define NN   10000     // nodes
#define NBAT 4         // batch
#define NE   160000    // edges
#define EPSV 1e-8f

typedef _Float16 f16;
typedef _Float16 f16x8 __attribute__((ext_vector_type(8)));
typedef float    f32x4 __attribute__((ext_vector_type(4)));

// ---------------------------------------------------------------------------
// degree + count accumulation (merged)
__global__ void k_degcnt(const float* __restrict__ ew, const int* __restrict__ row,
                         const int* __restrict__ col, float* __restrict__ dout,
                         float* __restrict__ din, int* __restrict__ cnt_out,
                         int* __restrict__ cnt_in) {
    int e = blockIdx.x * 256 + threadIdx.x;
    if (e < NE) {
        float w = ew[e];
        int r = row[e], c = col[e];
        atomicAdd(&dout[r], w);
        atomicAdd(&din[c], w);
        atomicAdd(&cnt_out[c], 1);   // A_out scatters to col
        atomicAdd(&cnt_in[r], 1);    // A_in  scatters to row
    }
}

__global__ void k_inv(float* __restrict__ dout, float* __restrict__ din) {
    int v = blockIdx.x * 256 + threadIdx.x;
    if (v < NN) {
        dout[v] = 1.f / (dout[v] + EPSV);
        din[v]  = 1.f / (din[v] + EPSV);
    }
}

// exclusive scan over N=10000 counts; blockIdx.x selects which CSR
__global__ void k_scan(const int* __restrict__ cnt_out, int* __restrict__ ptr_out, int* __restrict__ cur_out,
                       const int* __restrict__ cnt_in,  int* __restrict__ ptr_in,  int* __restrict__ cur_in) {
    const int* cnt = blockIdx.x ? cnt_in : cnt_out;
    int* ptr = blockIdx.x ? ptr_in : ptr_out;
    int* cur = blockIdx.x ? cur_in : cur_out;
    __shared__ int part[1024];
    int t = threadIdx.x;
    int c0 = t * 10, c1 = min(c0 + 10, NN);
    int s = 0;
    for (int i = c0; i < c1; i++) s += cnt[i];
    part[t] = s;
    __syncthreads();
    for (int off = 1; off < 1024; off <<= 1) {
        int v = (t >= off) ? part[t - off] : 0;
        __syncthreads();
        part[t] += v;
        __syncthreads();
    }
    int run = t ? part[t - 1] : 0;
    for (int i = c0; i < c1; i++) { ptr[i] = run; cur[i] = run; run += cnt[i]; }
    if (t == 1023) ptr[NN] = part[1023];
}

__global__ void k_fill(const int* __restrict__ row, const int* __restrict__ col,
                       const float* __restrict__ inv_out, const float* __restrict__ inv_in,
                       int* __restrict__ cur_out, int* __restrict__ srcs_out, float* __restrict__ w_out,
                       int* __restrict__ cur_in,  int* __restrict__ srcs_in,  float* __restrict__ w_in) {
    int e = blockIdx.x * 256 + threadIdx.x;
    if (e >= NE) return;
    int r = row[e], c = col[e];
    int po = atomicAdd(&cur_out[c], 1);
    srcs_out[po] = r;  w_out[po] = inv_out[r];
    int pi = atomicAdd(&cur_in[r], 1);
    srcs_in[pi] = c;   w_in[pi] = inv_in[c];
}

// ---------------------------------------------------------------------------
// build f16 concat rows: Xh16[node][0:64]=X, [64:128]=H   (node = b*NN+v)
__global__ void k_xh16(const float* __restrict__ X, const float* __restrict__ H,
                       f16* __restrict__ Xh) {
    int t = blockIdx.x * 256 + threadIdx.x;          // nBN*16 threads, 8 elems each
    int slot = t & 15;
    size_t node = (size_t)(t >> 4);
    int c0 = slot * 8;
    const float* src = (c0 < 64) ? (X + node * 64 + c0) : (H + node * 64 + (c0 - 64));
    float4 a = *(const float4*)src;
    float4 b = *(const float4*)(src + 4);
    f16x8 o;
    o[0] = (f16)a.x; o[1] = (f16)a.y; o[2] = (f16)a.z; o[3] = (f16)a.w;
    o[4] = (f16)b.x; o[5] = (f16)b.y; o[6] = (f16)b.z; o[7] = (f16)b.w;
    *(f16x8*)(Xh + node * 128 + c0) = o;
}

// ---------------------------------------------------------------------------
// f16 propagation, merged CSR pair: y[b,v,:] = sum_j w[j] * x[b,src[j],:]
template <int D>
__global__ __launch_bounds__(256) void k_prop16(
        const int* __restrict__ pA, const int* __restrict__ sA, const float* __restrict__ wA,
        const f16* __restrict__ xA, f16* __restrict__ yA,
        const int* __restrict__ pB, const int* __restrict__ sB, const float* __restrict__ wB,
        const f16* __restrict__ xB, f16* __restrict__ yB) {
    const int VEC = D / 8;   // f16x8 lanes per node
    int half = gridDim.x >> 1;
    bool second = blockIdx.x >= half;
    const int* ptr   = second ? pB : pA;
    const int* srcs  = second ? sB : sA;
    const float* wts = second ? wB : wA;
    const f16* x     = second ? xB : xA;
    f16* y           = second ? yB : yA;
    int tid = (second ? blockIdx.x - half : blockIdx.x) * 256 + threadIdx.x;
    int c8 = tid & (VEC - 1);
    int v  = (tid / VEC) % NN;
    int b  = tid / (VEC * NN);
    const f16* src = x + (size_t)b * NN * D + c8 * 8;
    int j0 = ptr[v], j1 = ptr[v + 1];
    float acc[8] = {};
#pragma unroll 4
    for (int j = j0; j < j1; j++) {
        float w = wts[j];
        f16x8 g = *(const f16x8*)(src + (size_t)srcs[j] * D);
#pragma unroll
        for (int q = 0; q < 8; q++) acc[q] += w * (float)g[q];
    }
    f16x8 o;
#pragma unroll
    for (int q = 0; q < 8; q++) o[q] = (f16)acc[q];
    ((f16x8*)y)[tid] = o;
}

// ---------------------------------------------------------------------------
// effective weights, TRANSPOSED + f16: Wt[g][o][kk], kk in [0,640)
//  blk0 (kk<128): W00+W10-W02-W12 ; blk1: W01 ; blk2: W11 ; blk3: 2*W02 ; blk4: 2*W12
__global__ void k_wprep16(const float* __restrict__ Wz, const float* __restrict__ Wr,
                          const float* __restrict__ Wh, f16* __restrict__ Wt) {
    int t = blockIdx.x * 256 + threadIdx.x;   // ((g*64+o)*640+kk)
    if (t >= 3 * 64 * 640) return;
    int kk = t % 640;
    int o  = (t / 640) & 63;
    int g  = t / (640 * 64);
    const float* W = (g == 0) ? Wz : (g == 1 ? Wr : Wh);
    int blk = kk >> 7, kin = kk & 127;
#define WIDX(d, k) W[(((d) * 3 + (k)) * 128 + kin) * 64 + o]
    float val;
    if (blk == 0)      val = WIDX(0, 0) + WIDX(1, 0) - WIDX(0, 2) - WIDX(1, 2);
    else if (blk == 1) val = WIDX(0, 1);
    else if (blk == 2) val = WIDX(1, 1);
    else if (blk == 3) val = 2.f * WIDX(0, 2);
    else               val = 2.f * WIDX(1, 2);
#undef WIDX
    Wt[t] = (f16)val;
}

// ---------------------------------------------------------------------------
// MFMA gate matmuls: [40000,640]@[640,64], A assembled from 10 f16 chunk sources
struct SrcTab16 {
    const f16* p[10];
    int ld[10];
    int co[10];
};

__device__ __forceinline__ float sigmf(float x) { return 1.f / (1.f + __expf(-x)); }
__device__ __forceinline__ float tanhfast(float x) {
    float e = __expf(2.f * x);
    return 1.f - 2.f / (e + 1.f);
}

// 64 rows x 64 cols per block, 4 waves (one 16-row stripe each)
__global__ __launch_bounds__(256) void k_gate_zr16(SrcTab16 tab,
        const f16* __restrict__ wtz, const f16* __restrict__ wtr,
        const float* __restrict__ bz, const float* __restrict__ br,
        const float* __restrict__ H, float* __restrict__ Z, f16* __restrict__ HR) {
    __shared__ f16 As[64 * 64];
    __shared__ f16 Ws[2][64 * 64];
    int tid = threadIdx.x;
    int l = tid & 63, w = tid >> 6;
    int g = l >> 4, li = l & 15;
    int rloc = w * 16 + li;
    int rb0 = blockIdx.x * 64;
    f32x4 accZ[4] = {}, accR[4] = {};
    for (int ch = 0; ch < 10; ch++) {
        // stage A tile (64x64 f16, XOR-swizzled)
        const f16* sp = tab.p[ch];
        int ld = tab.ld[ch], co = tab.co[ch];
#pragma unroll
        for (int i = 0; i < 2; i++) {
            int idx = i * 256 + tid;          // [0,512)
            int row = idx >> 3, slot = idx & 7;
            f16x8 v = *(const f16x8*)(sp + (size_t)(rb0 + row) * ld + co + slot * 8);
            int byte = row * 128 + ((slot * 16) ^ ((row & 7) << 4));
            *(f16x8*)((char*)As + byte) = v;
        }
        // stage both W chunks (each 64 rows(o) x 64 kk f16)
#pragma unroll
        for (int i = 0; i < 4; i++) {
            int idx = i * 256 + tid;          // [0,1024)
            int wsel = idx >> 9, id2 = idx & 511;
            int row = id2 >> 3, slot = id2 & 7;
            const f16* wp = (wsel ? wtr : wtz) + (size_t)row * 640 + ch * 64 + slot * 8;
            f16x8 v = *(const f16x8*)wp;
            int byte = row * 128 + ((slot * 16) ^ ((row & 7) << 4));
            *(f16x8*)((char*)Ws[wsel] + byte) = v;
        }
        __syncthreads();
#pragma unroll
        for (int kk2 = 0; kk2 < 2; kk2++) {
            int k = kk2 * 32 + g * 8;
            f16x8 af = *(const f16x8*)((char*)As + rloc * 128 + ((k * 2) ^ ((rloc & 7) << 4)));
#pragma unroll
            for (int ct = 0; ct < 4; ct++) {
                int c = ct * 16 + li;
                int wbyte = c * 128 + ((k * 2) ^ ((c & 7) << 4));
                f16x8 bzf = *(const f16x8*)((char*)Ws[0] + wbyte);
                f16x8 brf = *(const f16x8*)((char*)Ws[1] + wbyte);
                accZ[ct] = __builtin_amdgcn_mfma_f32_16x16x32_f16(af, bzf, accZ[ct], 0, 0, 0);
                accR[ct] = __builtin_amdgcn_mfma_f32_16x16x32_f16(af, brf, accR[ct], 0, 0, 0);
            }
        }
        __syncthreads();
    }
    // epilogue: C row = (lane>>4)*4 + reg, col = ct*16 + (lane&15)
#pragma unroll
    for (int ct = 0; ct < 4; ct++) {
        int c = ct * 16 + li;
        float zb = bz[c], rbv = br[c];
#pragma unroll
        for (int q = 0; q < 4; q++) {
            size_t row = (size_t)rb0 + w * 16 + g * 4 + q;
            float z = sigmf(accZ[ct][q] + zb);
            float r = sigmf(accR[ct][q] + rbv);
            Z[row * 64 + c] = z;
            HR[row * 64 + c] = (f16)(H[row * 64 + c] * r);
        }
    }
}

__global__ __launch_bounds__(256) void k_gate_h16(SrcTab16 tab,
        const f16* __restrict__ wth, const float* __restrict__ bh,
        const float* __restrict__ H, const float* __restrict__ Z,
        float* __restrict__ out) {
    __shared__ f16 As[64 * 64];
    __shared__ f16 Ws[64 * 64];
    int tid = threadIdx.x;
    int l = tid & 63, w = tid >> 6;
    int g = l >> 4, li = l & 15;
    int rloc = w * 16 + li;
    int rb0 = blockIdx.x * 64;
    f32x4 acc[4] = {};
    for (int ch = 0; ch < 10; ch++) {
        const f16* sp = tab.p[ch];
        int ld = tab.ld[ch], co = tab.co[ch];
#pragma unroll
        for (int i = 0; i < 2; i++) {
            int idx = i * 256 + tid;
            int row = idx >> 3, slot = idx & 7;
            f16x8 v = *(const f16x8*)(sp + (size_t)(rb0 + row) * ld + co + slot * 8);
            int byte = row * 128 + ((slot * 16) ^ ((row & 7) << 4));
            *(f16x8*)((char*)As + byte) = v;
        }
#pragma unroll
        for (int i = 0; i < 2; i++) {
            int idx = i * 256 + tid;
            int row = idx >> 3, slot = idx & 7;
            f16x8 v = *(const f16x8*)(wth + (size_t)row * 640 + ch * 64 + slot * 8);
            int byte = row * 128 + ((slot * 16) ^ ((row & 7) << 4));
            *(f16x8*)((char*)Ws + byte) = v;
        }
        __syncthreads();
#pragma unroll
        for (int kk2 = 0; kk2 < 2; kk2++) {
            int k = kk2 * 32 + g * 8;
            f16x8 af = *(const f16x8*)((char*)As + rloc * 128 + ((k * 2) ^ ((rloc & 7) << 4)));
#pragma unroll
            for (int ct = 0; ct < 4; ct++) {
                int c = ct * 16 + li;
                int wbyte = c * 128 + ((k * 2) ^ ((c & 7) << 4));
                f16x8 bf = *(const f16x8*)((char*)Ws + wbyte);
                acc[ct] = __builtin_amdgcn_mfma_f32_16x16x32_f16(af, bf, acc[ct], 0, 0, 0);
            }
        }
        __syncthreads();
    }
#pragma unroll
    for (int ct = 0; ct < 4; ct++) {
        int c = ct * 16 + li;
        float hb = bh[c];
#pragma unroll
        for (int q = 0; q < 4; q++) {
            size_t row = (size_t)rb0 + w * 16 + g * 4 + q;
            float ht = tanhfast(acc[ct][q] + hb);
            float z = Z[row * 64 + c];
            out[row * 64 + c] = z * H[row * 64 + c] + (1.f - z) * ht;
        }
    }
}

// ---------------------------------------------------------------------------
extern "C" void kernel_launch(void* const* d_in, const int* in_sizes, int n_in,
                              void* d_out, int out_size, void* d_ws, size_t ws_size,
                              hipStream_t stream) {
    const float* X  = (const float*)d_in[0];
    const float* H  = (const float*)d_in[1];
    const float* ew = (const float*)d_in[2];
    const float* Wz = (const float*)d_in[3];
    const float* bz = (const float*)d_in[4];
    const float* Wr = (const float*)d_in[5];
    const float* br = (const float*)d_in[6];
    const float* Wh = (const float*)d_in[7];
    const float* bh = (const float*)d_in[8];
    const int*   ei = (const int*)d_in[9];
    const int* row = ei;
    const int* col = ei + NE;
    float* out = (float*)d_out;

    char* ws = (char*)d_ws;
    size_t off = 0;
    auto alloc = [&](size_t bytes) -> void* {
        void* p = ws + off;
        off += (bytes + 255) & ~(size_t)255;
        return p;
    };
    float* degs     = (float*)alloc(2 * NN * 4);
    int*   cnts     = (int*)alloc(2 * NN * 4);
    int*   ptr_out  = (int*)alloc((NN + 1) * 4);
    int*   cur_out  = (int*)alloc(NN * 4);
    int*   srcs_out = (int*)alloc(NE * 4);
    float* w_out    = (float*)alloc(NE * 4);
    int*   ptr_in   = (int*)alloc((NN + 1) * 4);
    int*   cur_in   = (int*)alloc(NN * 4);
    int*   srcs_in  = (int*)alloc(NE * 4);
    float* w_in     = (float*)alloc(NE * 4);
    const size_t nBN = (size_t)NBAT * NN;
    f16* Xh16 = (f16*)alloc(nBN * 128 * 2);
    f16* P1o  = (f16*)alloc(nBN * 128 * 2);
    f16* P1i  = (f16*)alloc(nBN * 128 * 2);
    f16* S1o  = (f16*)alloc(nBN * 128 * 2);
    f16* S1i  = (f16*)alloc(nBN * 128 * 2);
    f16* HRb  = (f16*)alloc(nBN * 64 * 2);
    f16* T1o  = (f16*)alloc(nBN * 64 * 2);
    f16* T1i  = (f16*)alloc(nBN * 64 * 2);
    f16* T2o  = (f16*)alloc(nBN * 64 * 2);
    f16* T2i  = (f16*)alloc(nBN * 64 * 2);
    float* Zb = (float*)alloc(nBN * 64 * 4);
    f16* Wt   = (f16*)alloc(3 * 64 * 640 * 2);
    f16* wtz = Wt;
    f16* wtr = Wt + 64 * 640;
    f16* wth = Wt + 2 * 64 * 640;

    float* deg_out = degs;
    float* deg_in  = degs + NN;
    int* cnt_out = cnts;
    int* cnt_in  = cnts + NN;

    hipMemsetAsync(degs, 0, 2 * NN * 4, stream);
    hipMemsetAsync(cnts, 0, 2 * NN * 4, stream);

    int gE = (NE + 255) / 256;
    k_degcnt<<<gE, 256, 0, stream>>>(ew, row, col, deg_out, deg_in, cnt_out, cnt_in);
    k_inv<<<(NN + 255) / 256, 256, 0, stream>>>(deg_out, deg_in);
    k_scan<<<2, 1024, 0, stream>>>(cnt_out, ptr_out, cur_out, cnt_in, ptr_in, cur_in);
    k_fill<<<gE, 256, 0, stream>>>(row, col, deg_out, deg_in,
                                   cur_out, srcs_out, w_out, cur_in, srcs_in, w_in);

    // f16 concat build + weight prep
    k_xh16<<<(int)(nBN * 16 / 256), 256, 0, stream>>>(X, H, Xh16);
    k_wprep16<<<(3 * 64 * 640 + 255) / 256, 256, 0, stream>>>(Wz, Wr, Wh, Wt);

    int g128x2 = (int)(2 * nBN * 16 / 256);   // D=128, f16x8 lanes
    int g64x2  = (int)(2 * nBN * 8 / 256);    // D=64

    // P1o = A_out [X|H], P1i = A_in [X|H]
    k_prop16<128><<<g128x2, 256, 0, stream>>>(ptr_out, srcs_out, w_out, Xh16, P1o,
                                              ptr_in, srcs_in, w_in, Xh16, P1i);
    // S1o = A_out P1o, S1i = A_in P1i
    k_prop16<128><<<g128x2, 256, 0, stream>>>(ptr_out, srcs_out, w_out, P1o, S1o,
                                              ptr_in, srcs_in, w_in, P1i, S1i);

    SrcTab16 zr;
    {
        const f16* ps[10] = {Xh16, Xh16, P1o, P1o, P1i, P1i, S1o, S1o, S1i, S1i};
        int lds[10] = {128, 128, 128, 128, 128, 128, 128, 128, 128, 128};
        int cos_[10] = {0, 64, 0, 64, 0, 64, 0, 64, 0, 64};
        for (int i = 0; i < 10; i++) { zr.p[i] = ps[i]; zr.ld[i] = lds[i]; zr.co[i] = cos_[i]; }
    }
    int gMM = (int)(nBN / 64);
    k_gate_zr16<<<gMM, 256, 0, stream>>>(zr, wtz, wtr, bz, br, H, Zb, HRb);

    // props of HR (64-dim)
    k_prop16<64><<<g64x2, 256, 0, stream>>>(ptr_out, srcs_out, w_out, HRb, T1o,
                                            ptr_in, srcs_in, w_in, HRb, T1i);
    k_prop16<64><<<g64x2, 256, 0, stream>>>(ptr_out, srcs_out, w_out, T1o, T2o,
                                            ptr_in, srcs_in, w_in, T1i, T2i);

    SrcTab16 hh;
    {
        const f16* ps[10] = {Xh16, HRb, P1o, T1o, P1i, T1i, S1o, T2o, S1i, T2i};
        int lds[10] = {128, 64, 128, 64, 128, 64, 128, 64, 128, 64};
        int cos_[10] = {0, 0, 0, 0, 0, 0, 0, 0, 0, 0};
        for (int i = 0; i < 10; i++) { hh.p[i] = ps[i]; hh.ld[i] = lds[i]; hh.co[i] = cos_[i]; }
    }
    k_gate_h16<<<gMM, 256, 0, stream>>>(hh, wth, bh, H, Zb, out);
}

// Round 5
// 240.527 us; speedup vs baseline: 3.8121x; 1.0414x over previous
//
#include <hip/hip_runtime.h>
#include <math.h>

#define NN   10000     // nodes
#define NBAT 4         // batch
#define NE   160000    // edges
#define EPSV 1e-8f

typedef _Float16 f16;
typedef _Float16 f16x8 __attribute__((ext_vector_type(8)));
typedef float    f32x4 __attribute__((ext_vector_type(4)));

// ---------------------------------------------------------------------------
// degree + count accumulation (merged)
__global__ void k_degcnt(const float* __restrict__ ew, const int* __restrict__ row,
                         const int* __restrict__ col, float* __restrict__ dout,
                         float* __restrict__ din, int* __restrict__ cnt_out,
                         int* __restrict__ cnt_in) {
    int e = blockIdx.x * 256 + threadIdx.x;
    if (e < NE) {
        float w = ew[e];
        int r = row[e], c = col[e];
        atomicAdd(&dout[r], w);
        atomicAdd(&din[c], w);
        atomicAdd(&cnt_out[c], 1);   // A_out scatters to col
        atomicAdd(&cnt_in[r], 1);    // A_in  scatters to row
    }
}

// exclusive scan over N=10000 counts; blockIdx.x selects which CSR
__global__ void k_scan(const int* __restrict__ cnt_out, int* __restrict__ ptr_out, int* __restrict__ cur_out,
                       const int* __restrict__ cnt_in,  int* __restrict__ ptr_in,  int* __restrict__ cur_in) {
    const int* cnt = blockIdx.x ? cnt_in : cnt_out;
    int* ptr = blockIdx.x ? ptr_in : ptr_out;
    int* cur = blockIdx.x ? cur_in : cur_out;
    __shared__ int part[1024];
    int t = threadIdx.x;
    int c0 = t * 10, c1 = min(c0 + 10, NN);
    int s = 0;
    for (int i = c0; i < c1; i++) s += cnt[i];
    part[t] = s;
    __syncthreads();
    for (int off = 1; off < 1024; off <<= 1) {
        int v = (t >= off) ? part[t - off] : 0;
        __syncthreads();
        part[t] += v;
        __syncthreads();
    }
    int run = t ? part[t - 1] : 0;
    for (int i = c0; i < c1; i++) { ptr[i] = run; cur[i] = run; run += cnt[i]; }
    if (t == 1023) ptr[NN] = part[1023];
}

// fill CSR entries; weight = 1/(deg+eps) computed inline (k_inv folded in)
__global__ void k_fill(const int* __restrict__ row, const int* __restrict__ col,
                       const float* __restrict__ deg_out, const float* __restrict__ deg_in,
                       int* __restrict__ cur_out, int* __restrict__ srcs_out, float* __restrict__ w_out,
                       int* __restrict__ cur_in,  int* __restrict__ srcs_in,  float* __restrict__ w_in) {
    int e = blockIdx.x * 256 + threadIdx.x;
    if (e >= NE) return;
    int r = row[e], c = col[e];
    int po = atomicAdd(&cur_out[c], 1);
    srcs_out[po] = r;  w_out[po] = 1.f / (deg_out[r] + EPSV);
    int pi = atomicAdd(&cur_in[r], 1);
    srcs_in[pi] = c;   w_in[pi] = 1.f / (deg_in[c] + EPSV);
}

// ---------------------------------------------------------------------------
// build f16 concat rows: Xh16[node][0:64]=X, [64:128]=H   (node = b*NN+v)
__global__ void k_xh16(const float* __restrict__ X, const float* __restrict__ H,
                       f16* __restrict__ Xh) {
    int t = blockIdx.x * 256 + threadIdx.x;          // nBN*16 threads, 8 elems each
    int slot = t & 15;
    size_t node = (size_t)(t >> 4);
    int c0 = slot * 8;
    const float* src = (c0 < 64) ? (X + node * 64 + c0) : (H + node * 64 + (c0 - 64));
    float4 a = *(const float4*)src;
    float4 b = *(const float4*)(src + 4);
    f16x8 o;
    o[0] = (f16)a.x; o[1] = (f16)a.y; o[2] = (f16)a.z; o[3] = (f16)a.w;
    o[4] = (f16)b.x; o[5] = (f16)b.y; o[6] = (f16)b.z; o[7] = (f16)b.w;
    *(f16x8*)(Xh + node * 128 + c0) = o;
}

// ---------------------------------------------------------------------------
// f16 propagation, merged CSR pair: y[b,v,:] = sum_j w[j] * x[b,src[j],:]
// Edge loop batched in 8s: preload indices/weights, 8 independent gathers in
// flight (latency-bound pattern -> maximize outstanding loads).
template <int D>
__global__ __launch_bounds__(256) void k_prop16(
        const int* __restrict__ pA, const int* __restrict__ sA, const float* __restrict__ wA,
        const f16* __restrict__ xA, f16* __restrict__ yA,
        const int* __restrict__ pB, const int* __restrict__ sB, const float* __restrict__ wB,
        const f16* __restrict__ xB, f16* __restrict__ yB) {
    const int VEC = D / 8;   // f16x8 lanes per node
    int half = gridDim.x >> 1;
    bool second = blockIdx.x >= half;
    const int* ptr   = second ? pB : pA;
    const int* srcs  = second ? sB : sA;
    const float* wts = second ? wB : wA;
    const f16* x     = second ? xB : xA;
    f16* y           = second ? yB : yA;
    int tid = (second ? blockIdx.x - half : blockIdx.x) * 256 + threadIdx.x;
    int c8 = tid & (VEC - 1);
    int v  = (tid / VEC) % NN;
    int b  = tid / (VEC * NN);
    const f16* src = x + (size_t)b * NN * D + c8 * 8;
    int j0 = ptr[v], j1 = ptr[v + 1];
    float acc[8] = {};
    int j = j0;
    for (; j + 8 <= j1; j += 8) {
        int s[8]; float wv[8];
#pragma unroll
        for (int q = 0; q < 8; q++) { s[q] = srcs[j + q]; wv[q] = wts[j + q]; }
        f16x8 g[8];
#pragma unroll
        for (int q = 0; q < 8; q++) g[q] = *(const f16x8*)(src + (size_t)s[q] * D);
#pragma unroll
        for (int q = 0; q < 8; q++)
#pragma unroll
            for (int e = 0; e < 8; e++) acc[e] += wv[q] * (float)g[q][e];
    }
    for (; j < j1; j++) {
        float w = wts[j];
        f16x8 g = *(const f16x8*)(src + (size_t)srcs[j] * D);
#pragma unroll
        for (int e = 0; e < 8; e++) acc[e] += w * (float)g[e];
    }
    f16x8 o;
#pragma unroll
    for (int e = 0; e < 8; e++) o[e] = (f16)acc[e];
    ((f16x8*)y)[tid] = o;
}

// ---------------------------------------------------------------------------
// effective weights, TRANSPOSED + f16: Wt[g][o][kk], kk in [0,640)
//  blk0 (kk<128): W00+W10-W02-W12 ; blk1: W01 ; blk2: W11 ; blk3: 2*W02 ; blk4: 2*W12
__global__ void k_wprep16(const float* __restrict__ Wz, const float* __restrict__ Wr,
                          const float* __restrict__ Wh, f16* __restrict__ Wt) {
    int t = blockIdx.x * 256 + threadIdx.x;   // ((g*64+o)*640+kk)
    if (t >= 3 * 64 * 640) return;
    int kk = t % 640;
    int o  = (t / 640) & 63;
    int g  = t / (640 * 64);
    const float* W = (g == 0) ? Wz : (g == 1 ? Wr : Wh);
    int blk = kk >> 7, kin = kk & 127;
#define WIDX(d, k) W[(((d) * 3 + (k)) * 128 + kin) * 64 + o]
    float val;
    if (blk == 0)      val = WIDX(0, 0) + WIDX(1, 0) - WIDX(0, 2) - WIDX(1, 2);
    else if (blk == 1) val = WIDX(0, 1);
    else if (blk == 2) val = WIDX(1, 1);
    else if (blk == 3) val = 2.f * WIDX(0, 2);
    else               val = 2.f * WIDX(1, 2);
#undef WIDX
    Wt[t] = (f16)val;
}

// ---------------------------------------------------------------------------
// MFMA gate matmuls: [40000,640]@[640,64], A assembled from 10 f16 chunk sources
struct SrcTab16 {
    const f16* p[10];
    int ld[10];
    int co[10];
};

__device__ __forceinline__ float sigmf(float x) { return 1.f / (1.f + __expf(-x)); }
__device__ __forceinline__ float tanhfast(float x) {
    float e = __expf(2.f * x);
    return 1.f - 2.f / (e + 1.f);
}

// 64 rows x 64 cols per block, 4 waves; double-buffered LDS, 1 barrier/chunk:
// next-chunk global loads issue BEFORE the MFMA phase (latency hides under
// compute); regs->LDS store targets the OTHER buffer so no pre-store barrier.
__global__ __launch_bounds__(256) void k_gate_zr16(SrcTab16 tab,
        const f16* __restrict__ wtz, const f16* __restrict__ wtr,
        const float* __restrict__ bz, const float* __restrict__ br,
        const float* __restrict__ H, float* __restrict__ Z, f16* __restrict__ HR) {
    __shared__ f16 As[2][64 * 64];
    __shared__ f16 Ws[2][2][64 * 64];
    int tid = threadIdx.x;
    int l = tid & 63, w = tid >> 6;
    int g = l >> 4, li = l & 15;
    int rloc = w * 16 + li;
    int rb0 = blockIdx.x * 64;
    f32x4 accZ[4] = {}, accR[4] = {};
    f16x8 rA[2], rW[4];

    auto loadc = [&](int ch) {
        const f16* sp = tab.p[ch];
        int ld = tab.ld[ch], co = tab.co[ch];
#pragma unroll
        for (int i = 0; i < 2; i++) {
            int idx = i * 256 + tid;          // [0,512)
            int row = idx >> 3, slot = idx & 7;
            rA[i] = *(const f16x8*)(sp + (size_t)(rb0 + row) * ld + co + slot * 8);
        }
#pragma unroll
        for (int i = 0; i < 4; i++) {
            int idx = i * 256 + tid;          // [0,1024)
            int wsel = idx >> 9, id2 = idx & 511;
            int row = id2 >> 3, slot = id2 & 7;
            rW[i] = *(const f16x8*)((wsel ? wtr : wtz) + (size_t)row * 640 + ch * 64 + slot * 8);
        }
    };
    auto storec = [&](int buf) {
#pragma unroll
        for (int i = 0; i < 2; i++) {
            int idx = i * 256 + tid;
            int row = idx >> 3, slot = idx & 7;
            int byte = row * 128 + ((slot * 16) ^ ((row & 7) << 4));
            *(f16x8*)((char*)As[buf] + byte) = rA[i];
        }
#pragma unroll
        for (int i = 0; i < 4; i++) {
            int idx = i * 256 + tid;
            int wsel = idx >> 9, id2 = idx & 511;
            int row = id2 >> 3, slot = id2 & 7;
            int byte = row * 128 + ((slot * 16) ^ ((row & 7) << 4));
            *(f16x8*)((char*)Ws[buf][wsel] + byte) = rW[i];
        }
    };

    loadc(0); storec(0); __syncthreads();
    int cur = 0;
    for (int ch = 0; ch < 10; ch++) {
        if (ch + 1 < 10) loadc(ch + 1);
#pragma unroll
        for (int kk2 = 0; kk2 < 2; kk2++) {
            int k = kk2 * 32 + g * 8;
            f16x8 af = *(const f16x8*)((char*)As[cur] + rloc * 128 + ((k * 2) ^ ((rloc & 7) << 4)));
#pragma unroll
            for (int ct = 0; ct < 4; ct++) {
                int c = ct * 16 + li;
                int wbyte = c * 128 + ((k * 2) ^ ((c & 7) << 4));
                f16x8 bzf = *(const f16x8*)((char*)Ws[cur][0] + wbyte);
                f16x8 brf = *(const f16x8*)((char*)Ws[cur][1] + wbyte);
                accZ[ct] = __builtin_amdgcn_mfma_f32_16x16x32_f16(af, bzf, accZ[ct], 0, 0, 0);
                accR[ct] = __builtin_amdgcn_mfma_f32_16x16x32_f16(af, brf, accR[ct], 0, 0, 0);
            }
        }
        if (ch + 1 < 10) {
            storec(cur ^ 1);      // other buffer: no wave reads it this iter
            __syncthreads();      // publishes buf cur^1, and guards next-iter store of buf cur
            cur ^= 1;
        }
    }
    // epilogue: C row = (lane>>4)*4 + reg, col = ct*16 + (lane&15)
#pragma unroll
    for (int ct = 0; ct < 4; ct++) {
        int c = ct * 16 + li;
        float zb = bz[c], rbv = br[c];
#pragma unroll
        for (int q = 0; q < 4; q++) {
            size_t row = (size_t)rb0 + w * 16 + g * 4 + q;
            float z = sigmf(accZ[ct][q] + zb);
            float r = sigmf(accR[ct][q] + rbv);
            Z[row * 64 + c] = z;
            HR[row * 64 + c] = (f16)(H[row * 64 + c] * r);
        }
    }
}

__global__ __launch_bounds__(256) void k_gate_h16(SrcTab16 tab,
        const f16* __restrict__ wth, const float* __restrict__ bh,
        const float* __restrict__ H, const float* __restrict__ Z,
        float* __restrict__ out) {
    __shared__ f16 As[2][64 * 64];
    __shared__ f16 Ws[2][64 * 64];
    int tid = threadIdx.x;
    int l = tid & 63, w = tid >> 6;
    int g = l >> 4, li = l & 15;
    int rloc = w * 16 + li;
    int rb0 = blockIdx.x * 64;
    f32x4 acc[4] = {};
    f16x8 rA[2], rW[2];

    auto loadc = [&](int ch) {
        const f16* sp = tab.p[ch];
        int ld = tab.ld[ch], co = tab.co[ch];
#pragma unroll
        for (int i = 0; i < 2; i++) {
            int idx = i * 256 + tid;
            int row = idx >> 3, slot = idx & 7;
            rA[i] = *(const f16x8*)(sp + (size_t)(rb0 + row) * ld + co + slot * 8);
            rW[i] = *(const f16x8*)(wth + (size_t)row * 640 + ch * 64 + slot * 8);
        }
    };
    auto storec = [&](int buf) {
#pragma unroll
        for (int i = 0; i < 2; i++) {
            int idx = i * 256 + tid;
            int row = idx >> 3, slot = idx & 7;
            int byte = row * 128 + ((slot * 16) ^ ((row & 7) << 4));
            *(f16x8*)((char*)As[buf] + byte) = rA[i];
            *(f16x8*)((char*)Ws[buf] + byte) = rW[i];
        }
    };

    loadc(0); storec(0); __syncthreads();
    int cur = 0;
    for (int ch = 0; ch < 10; ch++) {
        if (ch + 1 < 10) loadc(ch + 1);
#pragma unroll
        for (int kk2 = 0; kk2 < 2; kk2++) {
            int k = kk2 * 32 + g * 8;
            f16x8 af = *(const f16x8*)((char*)As[cur] + rloc * 128 + ((k * 2) ^ ((rloc & 7) << 4)));
#pragma unroll
            for (int ct = 0; ct < 4; ct++) {
                int c = ct * 16 + li;
                int wbyte = c * 128 + ((k * 2) ^ ((c & 7) << 4));
                f16x8 bf = *(const f16x8*)((char*)Ws[cur] + wbyte);
                acc[ct] = __builtin_amdgcn_mfma_f32_16x16x32_f16(af, bf, acc[ct], 0, 0, 0);
            }
        }
        if (ch + 1 < 10) {
            storec(cur ^ 1);
            __syncthreads();
            cur ^= 1;
        }
    }
#pragma unroll
    for (int ct = 0; ct < 4; ct++) {
        int c = ct * 16 + li;
        float hb = bh[c];
#pragma unroll
        for (int q = 0; q < 4; q++) {
            size_t row = (size_t)rb0 + w * 16 + g * 4 + q;
            float ht = tanhfast(acc[ct][q] + hb);
            float z = Z[row * 64 + c];
            out[row * 64 + c] = z * H[row * 64 + c] + (1.f - z) * ht;
        }
    }
}

// ---------------------------------------------------------------------------
extern "C" void kernel_launch(void* const* d_in, const int* in_sizes, int n_in,
                              void* d_out, int out_size, void* d_ws, size_t ws_size,
                              hipStream_t stream) {
    const float* X  = (const float*)d_in[0];
    const float* H  = (const float*)d_in[1];
    const float* ew = (const float*)d_in[2];
    const float* Wz = (const float*)d_in[3];
    const float* bz = (const float*)d_in[4];
    const float* Wr = (const float*)d_in[5];
    const float* br = (const float*)d_in[6];
    const float* Wh = (const float*)d_in[7];
    const float* bh = (const float*)d_in[8];
    const int*   ei = (const int*)d_in[9];
    const int* row = ei;
    const int* col = ei + NE;
    float* out = (float*)d_out;

    char* ws = (char*)d_ws;
    size_t off = 0;
    auto alloc = [&](size_t bytes) -> void* {
        void* p = ws + off;
        off += (bytes + 255) & ~(size_t)255;
        return p;
    };
    float* degs     = (float*)alloc(2 * NN * 4);
    int*   cnts     = (int*)alloc(2 * NN * 4);
    int*   ptr_out  = (int*)alloc((NN + 1) * 4);
    int*   cur_out  = (int*)alloc(NN * 4);
    int*   srcs_out = (int*)alloc(NE * 4);
    float* w_out    = (float*)alloc(NE * 4);
    int*   ptr_in   = (int*)alloc((NN + 1) * 4);
    int*   cur_in   = (int*)alloc(NN * 4);
    int*   srcs_in  = (int*)alloc(NE * 4);
    float* w_in     = (float*)alloc(NE * 4);
    const size_t nBN = (size_t)NBAT * NN;
    f16* Xh16 = (f16*)alloc(nBN * 128 * 2);
    f16* P1o  = (f16*)alloc(nBN * 128 * 2);
    f16* P1i  = (f16*)alloc(nBN * 128 * 2);
    f16* S1o  = (f16*)alloc(nBN * 128 * 2);
    f16* S1i  = (f16*)alloc(nBN * 128 * 2);
    f16* HRb  = (f16*)alloc(nBN * 64 * 2);
    f16* T1o  = (f16*)alloc(nBN * 64 * 2);
    f16* T1i  = (f16*)alloc(nBN * 64 * 2);
    f16* T2o  = (f16*)alloc(nBN * 64 * 2);
    f16* T2i  = (f16*)alloc(nBN * 64 * 2);
    float* Zb = (float*)alloc(nBN * 64 * 4);
    f16* Wt   = (f16*)alloc(3 * 64 * 640 * 2);
    f16* wtz = Wt;
    f16* wtr = Wt + 64 * 640;
    f16* wth = Wt + 2 * 64 * 640;

    float* deg_out = degs;
    float* deg_in  = degs + NN;
    int* cnt_out = cnts;
    int* cnt_in  = cnts + NN;

    hipMemsetAsync(degs, 0, 2 * NN * 4, stream);
    hipMemsetAsync(cnts, 0, 2 * NN * 4, stream);

    int gE = (NE + 255) / 256;
    k_degcnt<<<gE, 256, 0, stream>>>(ew, row, col, deg_out, deg_in, cnt_out, cnt_in);
    k_scan<<<2, 1024, 0, stream>>>(cnt_out, ptr_out, cur_out, cnt_in, ptr_in, cur_in);
    k_fill<<<gE, 256, 0, stream>>>(row, col, deg_out, deg_in,
                                   cur_out, srcs_out, w_out, cur_in, srcs_in, w_in);

    // f16 concat build + weight prep
    k_xh16<<<(int)(nBN * 16 / 256), 256, 0, stream>>>(X, H, Xh16);
    k_wprep16<<<(3 * 64 * 640 + 255) / 256, 256, 0, stream>>>(Wz, Wr, Wh, Wt);

    int g128x2 = (int)(2 * nBN * 16 / 256);   // D=128, f16x8 lanes
    int g64x2  = (int)(2 * nBN * 8 / 256);    // D=64

    // P1o = A_out [X|H], P1i = A_in [X|H]
    k_prop16<128><<<g128x2, 256, 0, stream>>>(ptr_out, srcs_out, w_out, Xh16, P1o,
                                              ptr_in, srcs_in, w_in, Xh16, P1i);
    // S1o = A_out P1o, S1i = A_in P1i
    k_prop16<128><<<g128x2, 256, 0, stream>>>(ptr_out, srcs_out, w_out, P1o, S1o,
                                              ptr_in, srcs_in, w_in, P1i, S1i);

    SrcTab16 zr;
    {
        const f16* ps[10] = {Xh16, Xh16, P1o, P1o, P1i, P1i, S1o, S1o, S1i, S1i};
        int lds[10] = {128, 128, 128, 128, 128, 128, 128, 128, 128, 128};
        int cos_[10] = {0, 64, 0, 64, 0, 64, 0, 64, 0, 64};
        for (int i = 0; i < 10; i++) { zr.p[i] = ps[i]; zr.ld[i] = lds[i]; zr.co[i] = cos_[i]; }
    }
    int gMM = (int)(nBN / 64);
    k_gate_zr16<<<gMM, 256, 0, stream>>>(zr, wtz, wtr, bz, br, H, Zb, HRb);

    // props of HR (64-dim)
    k_prop16<64><<<g64x2, 256, 0, stream>>>(ptr_out, srcs_out, w_out, HRb, T1o,
                                            ptr_in, srcs_in, w_in, HRb, T1i);
    k_prop16<64><<<g64x2, 256, 0, stream>>>(ptr_out, srcs_out, w_out, T1o, T2o,
                                            ptr_in, srcs_in, w_in, T1i, T2i);

    SrcTab16 hh;
    {
        const f16* ps[10] = {Xh16, HRb, P1o, T1o, P1i, T1i, S1o, T2o, S1i, T2i};
        int lds[10] = {128, 64, 128, 64, 128, 64, 128, 64, 128, 64};
        int cos_[10] = {0, 0, 0, 0, 0, 0, 0, 0, 0, 0};
        for (int i = 0; i < 10; i++) { hh.p[i] = ps[i]; hh.ld[i] = lds[i]; hh.co[i] = cos_[i]; }
    }
    k_gate_h16<<<gMM, 256, 0, stream>>>(hh, wth, bh, H, Zb, out);
}